// Round 1
// baseline (374.648 us; speedup 1.0000x reference)
//
#include <hip/hip_runtime.h>
#include <hip/hip_bf16.h>

// Problem constants
#define NN 245      // tokens
#define NP 256      // padded tokens
#define HH 12       // heads
#define DD 64       // head dim
#define CC 768      // channels
#define NBUCKET 1698
#define MROWS (64 * NN)   // 15680

typedef __bf16 bf16x8 __attribute__((ext_vector_type(8)));
typedef float f32x4 __attribute__((ext_vector_type(4)));

#define MFMA(a, b, c) __builtin_amdgcn_mfma_f32_16x16x32_bf16(a, b, c, 0, 0, 0)

static __device__ __forceinline__ f32x4 fzero() {
    f32x4 z = {0.f, 0.f, 0.f, 0.f};
    return z;
}

static __device__ __forceinline__ bf16x8 cvt8(f32x4 lo, f32x4 hi) {
    bf16x8 r;
    #pragma unroll
    for (int i = 0; i < 4; ++i) { r[i] = (__bf16)lo[i]; r[i + 4] = (__bf16)hi[i]; }
    return r;
}

// async global->LDS, 16B per lane (wave-uniform LDS base + lane*16)
static __device__ __forceinline__ void gl_lds16(const __bf16* g, __bf16* l) {
    __builtin_amdgcn_global_load_lds(
        (const __attribute__((address_space(1))) void*)g,
        (__attribute__((address_space(3))) void*)l, 16, 0, 0);
}

// ---------------------------------------------------------------------------
// KC: fp32 -> bf16 bulk convert (n8 = elements/8)
__global__ __launch_bounds__(256) void kcvt(
    const float* __restrict__ src, __bf16* __restrict__ dst, int n8)
{
    int i = blockIdx.x * 256 + threadIdx.x;
    int stride = gridDim.x * 256;
    for (; i < n8; i += stride) {
        f32x4 a = *(const f32x4*)(src + (size_t)i * 8);
        f32x4 b = *(const f32x4*)(src + (size_t)i * 8 + 4);
        *(bf16x8*)(dst + (size_t)i * 8) = cvt8(a, b);
    }
}

// ---------------------------------------------------------------------------
// K0: bias'[g][n][m] = sum_h w_l[g,h] * rpe[h, rel_idx[n,m]] + b_l[g]
//     Output bf16. Pad positions = -30000 so softmax zeroes them.
__global__ __launch_bounds__(256) void k0_bias(
    const float* __restrict__ rpe, const int* __restrict__ relidx,
    const float* __restrict__ wl_, const float* __restrict__ bl_,
    __bf16* __restrict__ biasb)
{
    __shared__ float wl[144];
    __shared__ float bl[12];
    int t = threadIdx.x;
    if (t < 144) wl[t] = wl_[t];
    if (t < 12)  bl[t] = bl_[t];
    __syncthreads();
    int n = blockIdx.x;   // 0..255
    int m = t;            // 0..255
    float r[12];
    bool valid = (n < NN) && (m < NN);
    if (valid) {
        int idx = relidx[n * NN + m];
        #pragma unroll
        for (int h = 0; h < 12; ++h) r[h] = rpe[h * NBUCKET + idx];
    }
    #pragma unroll
    for (int g = 0; g < 12; ++g) {
        float o = -30000.f;
        if (valid) {
            o = bl[g];
            #pragma unroll
            for (int h = 0; h < 12; ++h) o += wl[g * 12 + h] * r[h];
        }
        biasb[(size_t)(g * 256 + n) * 256 + m] = (__bf16)o;
    }
}

// ---------------------------------------------------------------------------
// 16-MFMA quadrant compute for one 128x128 tile's K-step from one LDS buffer.
static __device__ __forceinline__ void mfma_step(
    const __bf16* __restrict__ sAb, const __bf16* __restrict__ sBb,
    int roff, int boff, f32x4 acc[4][4])
{
    bf16x8 af[4], bfr[4];
    #pragma unroll
    for (int q = 0; q < 4; ++q) af[q]  = *(const bf16x8*)(sAb + roff + q * 512);
    #pragma unroll
    for (int n = 0; n < 4; ++n) bfr[n] = *(const bf16x8*)(sBb + boff + n * 512);
    __builtin_amdgcn_s_setprio(1);
    #pragma unroll
    for (int q = 0; q < 4; ++q)
        #pragma unroll
        for (int n = 0; n < 4; ++n)
            acc[q][n] = MFMA(af[q], bfr[n], acc[q][n]);
    __builtin_amdgcn_s_setprio(0);
}

// ---------------------------------------------------------------------------
// gemm128: 128x128-tile NT GEMM (bf16 in, K=768, BK=32) + T1 XCD swizzle.
// R7: T3-minimum 2-phase double-buffered K-loop. Old structure fully drained
// the global_load_lds queue between two barriers every iter (zero intra-block
// overlap) while VGPR+AGPR (~140 regs) caps residency at 2 blocks/CU, so the
// load latency was exposed. Now: STAGE(next)->ds_read(cur)->MFMA->barrier,
// one barrier per K-step, stage latency hidden under compute.
template<int EPI>
__global__ __launch_bounds__(256) void gemm128(
    const __bf16* __restrict__ A, const __bf16* __restrict__ Bw,
    __bf16* __restrict__ Q, __bf16* __restrict__ Kb, __bf16* __restrict__ VT,
    const float* __restrict__ bproj, float* __restrict__ outp)
{
    __shared__ __attribute__((aligned(16))) __bf16 sA[2][128 * 32];
    __shared__ __attribute__((aligned(16))) __bf16 sB[2][128 * 32];
    int tid = threadIdx.x, lane = tid & 63, wave = tid >> 6;

    // T1: XCD-chunked bijective swizzle (m204; hw round-robins wg%8 -> XCD)
    int gx = gridDim.x;
    int nwg = gx * gridDim.y;
    int wg = blockIdx.y * gx + blockIdx.x;
    int q8 = nwg >> 3, r8 = nwg & 7;
    int xcd = wg & 7, idx = wg >> 3;
    int swz = (xcd < r8 ? xcd * (q8 + 1) : r8 * (q8 + 1) + (xcd - r8) * q8) + idx;
    int et = swz % gx, mt = swz / gx;
    int m0 = mt * 128, e0 = et * 128;

    int r1 = tid >> 2, chunk = tid & 3;
    int gar1 = m0 + r1;        if (gar1 >= MROWS) gar1 = MROWS - 1;
    int gar2 = m0 + 64 + r1;   if (gar2 >= MROWS) gar2 = MROWS - 1;
    const __bf16* aA1 = A  + (size_t)gar1 * CC + chunk * 8;
    const __bf16* aA2 = A  + (size_t)gar2 * CC + chunk * 8;
    const __bf16* aB1 = Bw + (size_t)(e0 + r1) * CC + chunk * 8;
    const __bf16* aB2 = Bw + (size_t)(e0 + 64 + r1) * CC + chunk * 8;
    int off = tid * 8;

    int wr = wave >> 1, wc = wave & 1;
    int lrow = lane & 15, lk = (lane >> 4) * 8;
    int roff = (wr * 64 + lrow) * 32 + lk;
    int boff = (wc * 64 + lrow) * 32 + lk;

    f32x4 acc[4][4];
    #pragma unroll
    for (int q = 0; q < 4; ++q)
        #pragma unroll
        for (int n = 0; n < 4; ++n) acc[q][n] = fzero();

    // prologue: stage tile 0 into buf0
    gl_lds16(aA1, &sA[0][off]);
    gl_lds16(aA2, &sA[0][off + 2048]);
    gl_lds16(aB1, &sB[0][off]);
    gl_lds16(aB2, &sB[0][off + 2048]);
    __syncthreads();   // compiler emits vmcnt(0) drain here

    for (int it = 0; it < 24; it += 2) {
        // phase A: stage tile it+1 -> buf1, compute buf0 (tile it)
        gl_lds16(aA1 + (it + 1) * 32, &sA[1][off]);
        gl_lds16(aA2 + (it + 1) * 32, &sA[1][off + 2048]);
        gl_lds16(aB1 + (it + 1) * 32, &sB[1][off]);
        gl_lds16(aB2 + (it + 1) * 32, &sB[1][off + 2048]);
        mfma_step(sA[0], sB[0], roff, boff, acc);
        __syncthreads();   // buf1 staged (vmcnt0) + everyone done reading buf0

        // phase B: stage tile it+2 -> buf0 (if any), compute buf1 (tile it+1)
        if (it + 2 < 24) {
            gl_lds16(aA1 + (it + 2) * 32, &sA[0][off]);
            gl_lds16(aA2 + (it + 2) * 32, &sA[0][off + 2048]);
            gl_lds16(aB1 + (it + 2) * 32, &sB[0][off]);
            gl_lds16(aB2 + (it + 2) * 32, &sB[0][off + 2048]);
        }
        mfma_step(sA[1], sB[1], roff, boff, acc);
        __syncthreads();
    }

    int col = lane & 15, rbs = (lane >> 4) * 4;
    #pragma unroll
    for (int q = 0; q < 4; ++q) {
        int gmb = m0 + wr * 64 + q * 16 + rbs;
        #pragma unroll
        for (int n = 0; n < 4; ++n) {
            int e = e0 + wc * 64 + n * 16 + col;
            if (EPI == 0) {
                int which = e / CC;
                int h = (e % CC) >> 6;
                int d = e & 63;
                #pragma unroll
                for (int r = 0; r < 4; ++r) {
                    int gm = gmb + r;
                    if (gm < MROWS) {
                        int bidx = gm / NN, nn = gm - bidx * NN;
                        float v = acc[q][n][r];
                        if (which == 0)
                            Q[((size_t)(bidx * 12 + h) * NP + nn) * 64 + d] = (__bf16)(v * 0.125f);
                        else if (which == 1)
                            Kb[((size_t)(bidx * 12 + h) * NP + nn) * 64 + d] = (__bf16)v;
                        else
                            VT[((size_t)(bidx * 12 + h) * 64 + d) * NP + nn] = (__bf16)v;
                    }
                }
            } else {
                float bv = bproj[e];
                #pragma unroll
                for (int r = 0; r < 4; ++r) {
                    int gm = gmb + r;
                    if (gm < MROWS)
                        outp[(size_t)gm * CC + e] = acc[q][n][r] + bv;
                }
            }
        }
    }
}

// ---------------------------------------------------------------------------
// K2c: S[b][g][n][m] = sum_h w_l[g,h]*(q_h.k_h) + bias'[g][n][m]  (bf16)
// Per-wave math identical to verified k2 (16n x 16m, acc[12]); new geometry:
// 512 thr = 8 waves (2n x 4m) -> 32n x 64m block tile; launch_bounds(512,4)
// caps VGPR at 128 (4 waves/SIMD, was 172/10.7% occupancy); XCD swizzle
// groups 8 consecutive b per XCD so the 786KB/b Q/K slice is L2-resident.
__global__ __launch_bounds__(512, 4) void k2c_qk(
    const __bf16* __restrict__ Q, const __bf16* __restrict__ Kb,
    const __bf16* __restrict__ biasb, const float* __restrict__ wl_,
    __bf16* __restrict__ S)
{
    __shared__ float wl[144];
    int tid = threadIdx.x, wave = tid >> 6, lane = tid & 63;
    if (tid < 144) wl[tid] = wl_[tid];
    __syncthreads();

    // XCD swizzle: 2048 blocks (%8==0 -> simple bijective), 256/XCD,
    // 8 consecutive b per XCD (32 blocks per b).
    int wg = blockIdx.x;
    int L = (wg & 7) * 256 + (wg >> 3);
    int b = L >> 5, rem = L & 31;
    int mq = rem & 3, nt = rem >> 2;          // mq 0..3, nt 0..7
    int wn = wave >> 2, wm = wave & 3;
    int n0 = nt * 32 + wn * 16;
    int m0 = mq * 64 + wm * 16;

    int lrow = lane & 15, lk = (lane >> 4) * 8;
    f32x4 acc[12];
    #pragma unroll
    for (int h = 0; h < 12; ++h) acc[h] = fzero();
    #pragma unroll
    for (int h = 0; h < 12; ++h) {
        const __bf16* qb = Q  + ((size_t)(b * 12 + h) * NP + n0 + lrow) * 64 + lk;
        const __bf16* kb = Kb + ((size_t)(b * 12 + h) * NP + m0 + lrow) * 64 + lk;
        bf16x8 a0 = *(const bf16x8*)qb;
        bf16x8 b0 = *(const bf16x8*)kb;
        bf16x8 a1 = *(const bf16x8*)(qb + 32);
        bf16x8 b1 = *(const bf16x8*)(kb + 32);
        acc[h] = MFMA(a0, b0, acc[h]);
        acc[h] = MFMA(a1, b1, acc[h]);
    }
    int col = lane & 15, rb = (lane >> 4) * 4;
    #pragma unroll
    for (int g = 0; g < 12; ++g) {
        f32x4 s = fzero();
        #pragma unroll
        for (int h = 0; h < 12; ++h) {
            float w = wl[g * 12 + h];
            s += acc[h] * w;
        }
        #pragma unroll
        for (int r = 0; r < 4; ++r) {
            int n = n0 + rb + r;
            int m = m0 + col;
            float v = s[r] + (float)biasb[(size_t)(g * 256 + n) * 256 + m];
            S[((size_t)(b * 12 + g) * NP + n) * NP + m] = (__bf16)v;
        }
    }
}

// ---------------------------------------------------------------------------
// K34 fused: softmax (P in registers) + w_w post-mix (2 gp at a time into
// 16.5KB LDS) + PV MFMA. Block = (b, 16 n-rows), 512 threads = 8 waves.
// (verified R6 version)
__global__ __launch_bounds__(512, 3) void k34_smx_pv(
    const __bf16* __restrict__ S, const __bf16* __restrict__ VT,
    const float* __restrict__ ww_, const float* __restrict__ bw_,
    __bf16* __restrict__ aout)
{
    __shared__ __attribute__((aligned(16))) __bf16 Pp[2][16][264];
    __shared__ float ww[144];
    __shared__ float bw[12];
    int tid = threadIdx.x;
    if (tid < 144) ww[tid] = ww_[tid];
    if (tid >= 256 && tid < 268) bw[tid - 256] = bw_[tid - 256];

    // XCD swizzle: 16 same-b blocks -> same XCD
    int W = blockIdx.x;                 // 0..1023
    int g8 = W & 7, kk = W >> 3;
    int L = (kk >> 4) * 128 + g8 * 16 + (kk & 15);   // bijective
    int b = L >> 4, nt = L & 15;
    int n0 = nt * 16;

    int n = tid >> 5, ms = tid & 31;
    int lane = tid & 63, wave = tid >> 6;

    // ---- Phase A: per-(g,n)-row softmax; P kept in registers -------------
    float P[12][8];
    #pragma unroll
    for (int g = 0; g < 12; ++g) {
        const __bf16* rowp = S + ((size_t)(b * 12 + g) * NP + n0 + n) * NP + ms * 8;
        bf16x8 sv = *(const bf16x8*)rowp;
        float v[8];
        float mx = -1e30f;
        #pragma unroll
        for (int j = 0; j < 8; ++j) {
            v[j] = (ms * 8 + j < NN) ? (float)sv[j] : -1e30f;
            mx = fmaxf(mx, v[j]);
        }
        #pragma unroll
        for (int o = 16; o > 0; o >>= 1) mx = fmaxf(mx, __shfl_xor(mx, o));
        float sum = 0.f;
        #pragma unroll
        for (int j = 0; j < 8; ++j) {
            float e = (ms * 8 + j < NN) ? __expf(v[j] - mx) : 0.f;
            P[g][j] = e;
            sum += e;
        }
        #pragma unroll
        for (int o = 16; o > 0; o >>= 1) sum += __shfl_xor(sum, o);
        float inv = 1.f / sum;
        #pragma unroll
        for (int j = 0; j < 8; ++j) P[g][j] *= inv;
    }
    __syncthreads();   // also covers ww/bw loads

    // ---- Phase B: 6 chunks of {mix 2 gp -> LDS, PV MFMA} -----------------
    int dt = wave >> 1, wgp = wave & 1;
    int lrow = lane & 15, lk = (lane >> 4) * 8;
    int col = lane & 15, rb = (lane >> 4) * 4;
    #pragma unroll
    for (int c = 0; c < 6; ++c) {
        #pragma unroll
        for (int gi = 0; gi < 2; ++gi) {
            int gp = c * 2 + gi;
            bf16x8 o;
            #pragma unroll
            for (int j = 0; j < 8; ++j) {
                float a = bw[gp];
                #pragma unroll
                for (int g = 0; g < 12; ++g) a += ww[gp * 12 + g] * P[g][j];
                o[j] = (__bf16)((ms * 8 + j < NN) ? a : 0.f);
            }
            *(bf16x8*)&Pp[gi][n][ms * 8] = o;
        }
        __syncthreads();
        int gp = c * 2 + wgp;
        f32x4 acc = fzero();
        const __bf16* vb = VT + ((size_t)(b * 12 + gp) * 64 + dt * 16 + lrow) * NP + lk;
        #pragma unroll
        for (int kt = 0; kt < 8; ++kt) {
            bf16x8 av = *(const bf16x8*)&Pp[wgp][lrow][kt * 32 + lk];
            bf16x8 bv = *(const bf16x8*)(vb + kt * 32);
            acc = MFMA(av, bv, acc);
        }
        #pragma unroll
        for (int r = 0; r < 4; ++r) {
            int gn = n0 + rb + r;
            if (gn < NN)
                aout[((size_t)b * NN + gn) * CC + gp * 64 + dt * 16 + col] = (__bf16)acc[r];
        }
        __syncthreads();   // Pp consumed; safe to overwrite next chunk
    }
}

// ---------------------------------------------------------------------------
extern "C" void kernel_launch(void* const* d_in, const int* in_sizes, int n_in,
                              void* d_out, int out_size, void* d_ws, size_t ws_size,
                              hipStream_t stream)
{
    (void)in_sizes; (void)n_in; (void)out_size; (void)ws_size;
    const float* x     = (const float*)d_in[0];
    const float* wqkv  = (const float*)d_in[1];
    const float* wproj = (const float*)d_in[2];
    const float* bproj = (const float*)d_in[3];
    const float* wl    = (const float*)d_in[4];
    const float* bl    = (const float*)d_in[5];
    const float* ww    = (const float*)d_in[6];
    const float* bw    = (const float*)d_in[7];
    const float* rpe   = (const float*)d_in[8];
    const int*   rel   = (const int*)d_in[9];

    char* ws = (char*)d_ws;
    const size_t SZ_QKV = (size_t)64 * 12 * 256 * 64 * 2;   // 25,165,824 B
    const size_t SZ_S   = (size_t)64 * 12 * 256 * 256 * 2;  // 100,663,296 B
    __bf16* Q     = (__bf16*)(ws);
    __bf16* Kb    = (__bf16*)(ws + SZ_QKV);
    __bf16* VT    = (__bf16*)(ws + 2 * SZ_QKV);
    __bf16* biasb = (__bf16*)(ws + 3 * SZ_QKV);              // 1.5 MB (bf16)
    char*   sreg  = ws + 3 * SZ_QKV + (size_t)12 * 256 * 256 * 4;
    __bf16* S     = (__bf16*)sreg;
    // xb/wb alias into the S region (dead before k2c writes S)
    __bf16* xb    = (__bf16*)sreg;                               // 24.1 MB
    __bf16* wb    = (__bf16*)(sreg + (size_t)MROWS * CC * 2);    //  3.5 MB
    __bf16* wpb   = (__bf16*)(ws + 3 * SZ_QKV + (size_t)12 * 256 * 256 * 4 + SZ_S);
    __bf16* aout  = Q;  // Q dead after k2c; reuse as attn-out

    // zero VT so pad columns (m>=245) are 0 (P' is 0 there; avoid 0*NaN)
    hipMemsetAsync(VT, 0, SZ_QKV, stream);
    kcvt<<<dim3(2048), 256, 0, stream>>>(x,     xb,  MROWS * CC / 8);
    kcvt<<<dim3(864),  256, 0, stream>>>(wqkv,  wb,  3 * CC * CC / 8);
    kcvt<<<dim3(288),  256, 0, stream>>>(wproj, wpb, CC * CC / 8);
    k0_bias<<<dim3(256), 256, 0, stream>>>(rpe, rel, wl, bl, biasb);
    gemm128<0><<<dim3(18, 123), 256, 0, stream>>>(xb, wb, Q, Kb, VT, nullptr, nullptr);
    k2c_qk<<<dim3(2048), 512, 0, stream>>>(Q, Kb, biasb, wl, S);
    k34_smx_pv<<<dim3(1024), 512, 0, stream>>>(S, VT, ww, bw, aout);
    gemm128<1><<<dim3(6, 123), 256, 0, stream>>>(aout, wpb, nullptr, nullptr, nullptr,
                                                 bproj, (float*)d_out);
}